// Round 1
// baseline (164.748 us; speedup 1.0000x reference)
//
#include <hip/hip_runtime.h>

// Problem constants (ACmix: b=2, C=64, d=8, w=32, h=32)
// HEAD=4, HEAD_DIM=16, K_ATT=7, PAD=3, fh=2, fw=4 -> H2=64, W2=128, L=8192

// ---------------------------------------------------------------------------
// Kernel 1: q/k/v 1x1 convs.  q[b,c,l] = b1[c] + sum_ci w1[c,ci]*x[b,ci,l]
// Thread owns one (b,l); x[0..63] in registers; weights are wave-uniform
// (s_load path).  Grid: 512 blocks = 2 b * 32 ltiles * 8 cchunks(8 ch each).
// ---------------------------------------------------------------------------
__global__ __launch_bounds__(256) void qkv_kernel(
    const float* __restrict__ x,
    const float* __restrict__ w1, const float* __restrict__ b1,
    const float* __restrict__ w2, const float* __restrict__ b2,
    const float* __restrict__ w3, const float* __restrict__ b3,
    float* __restrict__ q, float* __restrict__ k, float* __restrict__ v)
{
    int bx = blockIdx.x;
    int cchunk = bx & 7;          // 8 chunks of 8 output channels
    int ltile  = (bx >> 3) & 31;  // 32 tiles of 256
    int b      = bx >> 8;         // 2 batches
    int l = ltile * 256 + threadIdx.x;

    const float* xb = x + (size_t)b * 64 * 8192 + l;
    float xr[64];
#pragma unroll
    for (int ci = 0; ci < 64; ++ci) xr[ci] = xb[(size_t)ci * 8192];

    for (int cc = 0; cc < 8; ++cc) {
        int c = cchunk * 8 + cc;
        float a1 = b1[c], a2 = b2[c], a3 = b3[c];
        const float* w1r = w1 + c * 64;
        const float* w2r = w2 + c * 64;
        const float* w3r = w3 + c * 64;
#pragma unroll
        for (int ci = 0; ci < 64; ++ci) {
            float xv = xr[ci];
            a1 = fmaf(w1r[ci], xv, a1);
            a2 = fmaf(w2r[ci], xv, a2);
            a3 = fmaf(w3r[ci], xv, a3);
        }
        size_t o = (size_t)(b * 64 + c) * 8192 + l;
        q[o] = a1; k[o] = a2; v[o] = a3;
    }
}

// ---------------------------------------------------------------------------
// Kernel 2: attention branch.  out = rate1 * out_att.
// Per block: one n=(b,head), one 16x16 pixel tile of the (64,128) image.
// LDS holds kp = k - pe (pe computed from source coords; the q.pe_center
// term is constant over the 49 window positions so it cancels in softmax)
// and v, both with +-3 reflect halo: [16][22][23] each = 64,768 B total.
// ---------------------------------------------------------------------------
__global__ __launch_bounds__(256) void att_kernel(
    const float* __restrict__ q, const float* __restrict__ k,
    const float* __restrict__ v,
    const float* __restrict__ wp, const float* __restrict__ bp,
    const float* __restrict__ rate1p, float* __restrict__ out)
{
    __shared__ float kp[16][22][23];
    __shared__ float vt[16][22][23];

    int bx = blockIdx.x;          // 8 n * 4 yt * 8 xt = 256
    int xt = bx & 7;
    int yt = (bx >> 3) & 3;
    int n  = bx >> 5;
    int head = n & 3;
    int b    = n >> 2;
    int y0 = yt * 16, x0 = xt * 16;

    // ---- load kp / v tiles (with reflect) ----
    const int NELEM = 16 * 22 * 22;
    for (int e = threadIdx.x; e < NELEM; e += 256) {
        int c   = e / 484;        // 22*22
        int rem = e % 484;
        int ty = rem / 22, tx = rem % 22;
        int sy = y0 + ty - 3; if (sy < 0) sy = -sy; else if (sy >= 64)  sy = 126 - sy;
        int sx = x0 + tx - 3; if (sx < 0) sx = -sx; else if (sx >= 128) sx = 254 - sx;
        int l = sy * 128 + sx;
        size_t o = (size_t)(b * 64 + head * 16 + c) * 8192 + l;
        // pe(c, l): derived from original (d,w,h) coords of l
        int dd = l >> 10, r2 = l & 1023, ww = r2 >> 5, hh = r2 & 31;
        float ld = dd * (2.0f / 7.0f)  - 1.0f;
        float lw = ww * (2.0f / 31.0f) - 1.0f;
        float lh = hh * (2.0f / 31.0f) - 1.0f;
        float pe = bp[c];
        pe = fmaf(wp[c * 3 + 0], ld, pe);
        pe = fmaf(wp[c * 3 + 1], lw, pe);
        pe = fmaf(wp[c * 3 + 2], lh, pe);
        kp[c][ty][tx] = k[o] - pe;
        vt[c][ty][tx] = v[o];
    }
    __syncthreads();

    // ---- per-pixel attention ----
    int tx = threadIdx.x & 15, ty = threadIdx.x >> 4;
    int y = y0 + ty, x = x0 + tx;
    int l = y * 128 + x;

    float qc[16];
#pragma unroll
    for (int c = 0; c < 16; ++c)
        qc[c] = q[(size_t)(b * 64 + head * 16 + c) * 8192 + l] * 0.25f; // *HEAD_DIM^-0.5

    float lg[49];
#pragma unroll
    for (int kk = 0; kk < 49; ++kk) {
        int i = kk / 7, j = kk % 7;
        float acc = 0.f;
#pragma unroll
        for (int c = 0; c < 16; ++c)
            acc = fmaf(qc[c], kp[c][ty + i][tx + j], acc);
        lg[kk] = acc;
    }
    float mx = lg[0];
#pragma unroll
    for (int kk = 1; kk < 49; ++kk) mx = fmaxf(mx, lg[kk]);
    float se = 0.f;
#pragma unroll
    for (int kk = 0; kk < 49; ++kk) { lg[kk] = __expf(lg[kk] - mx); se += lg[kk]; }
    float scale = rate1p[0] / se;

#pragma unroll
    for (int c = 0; c < 16; ++c) {
        float acc = 0.f;
#pragma unroll
        for (int kk = 0; kk < 49; ++kk) {
            int i = kk / 7, j = kk % 7;
            acc = fmaf(lg[kk], vt[c][ty + i][tx + j], acc);
        }
        out[(size_t)(b * 64 + head * 16 + c) * 8192 + l] = acc * scale;
    }
}

// ---------------------------------------------------------------------------
// Kernel 3: conv-mixing branch + combine.  out += rate2 * (depconv + bdep).
// f_conv[b, c144=m*16+hd, y2, x2] (spatial (8,1024)) is recomputed on the fly
// from q/k/v during the LDS load (fc: 12 MACs/elem), avoiding a whole kernel.
// Block: one (b, group g, x-tile of 128).  Tile LDS: f[9ch][8][130] = 37.4 KB.
// Output channels o = 4g..4g+3 use input channels 9g..9g+8 (groups=16).
// ---------------------------------------------------------------------------
__global__ __launch_bounds__(256) void conv_kernel(
    const float* __restrict__ q, const float* __restrict__ k,
    const float* __restrict__ v,
    const float* __restrict__ wfc,
    const float* __restrict__ wdep, const float* __restrict__ bdep,
    const float* __restrict__ rate2p, float* __restrict__ out)
{
    __shared__ float ft[9][8][130];

    int bx = blockIdx.x;          // 2 b * 16 g * 8 xt = 256
    int xt = bx & 7;
    int g  = (bx >> 3) & 15;
    int b  = bx >> 7;
    int x0 = xt * 128;

    // ---- load f tile (recompute fc on the fly) ----
    const int NE = 9 * 8 * 130;
    for (int e = threadIdx.x; e < NE; e += 256) {
        int i   = e / 1040;       // 8*130
        int rem = e % 1040;
        int y = rem / 130, xx = rem % 130;
        int gx = x0 + xx - 1;     // zero pad at x2 edges
        float val = 0.f;
        if (gx >= 0 && gx < 1024) {
            int c144 = g * 9 + i;
            int m  = c144 >> 4;
            int hd = c144 & 15;
            int l  = y * 1024 + gx;
            float acc = 0.f;
#pragma unroll
            for (int hh = 0; hh < 4; ++hh) {
                size_t o = (size_t)(b * 64 + hh * 16 + hd) * 8192 + l;
                acc = fmaf(wfc[m * 12 + 0 + hh], q[o], acc);
                acc = fmaf(wfc[m * 12 + 4 + hh], k[o], acc);
                acc = fmaf(wfc[m * 12 + 8 + hh], v[o], acc);
            }
            val = acc;
        }
        ft[i][y][xx] = val;
    }
    __syncthreads();

    // ---- depthwise 3x3 (general weights) over (y2=8, x2 tile=128) ----
    int xl = threadIdx.x & 127;
    int op = threadIdx.x >> 7;    // wave-uniform: waves 0,1 -> 0; 2,3 -> 1
    float rate2 = rate2p[0];

    float acc[2][8];
#pragma unroll
    for (int oo = 0; oo < 2; ++oo)
#pragma unroll
        for (int y = 0; y < 8; ++y) acc[oo][y] = 0.f;

    for (int i = 0; i < 9; ++i) {
        float fr[10][3];
#pragma unroll
        for (int dx = 0; dx < 3; ++dx) { fr[0][dx] = 0.f; fr[9][dx] = 0.f; }
#pragma unroll
        for (int y = 0; y < 8; ++y)
#pragma unroll
            for (int dx = 0; dx < 3; ++dx)
                fr[y + 1][dx] = ft[i][y][xl + dx];
#pragma unroll
        for (int oo = 0; oo < 2; ++oo) {
            int o = g * 4 + op * 2 + oo;
#pragma unroll
            for (int ky = 0; ky < 3; ++ky)
#pragma unroll
                for (int kx = 0; kx < 3; ++kx) {
                    float wv = wdep[((o * 9 + i) * 3 + ky) * 3 + kx];
#pragma unroll
                    for (int y = 0; y < 8; ++y)
                        acc[oo][y] = fmaf(wv, fr[y + ky][kx], acc[oo][y]);
                }
        }
    }

#pragma unroll
    for (int oo = 0; oo < 2; ++oo) {
        int o = g * 4 + op * 2 + oo;
        float bd = bdep[o];
#pragma unroll
        for (int y = 0; y < 8; ++y) {
            size_t idx = (size_t)(b * 64 + o) * 8192 + y * 1024 + x0 + xl;
            out[idx] = out[idx] + rate2 * (acc[oo][y] + bd);
        }
    }
}

// ---------------------------------------------------------------------------
extern "C" void kernel_launch(void* const* d_in, const int* in_sizes, int n_in,
                              void* d_out, int out_size, void* d_ws, size_t ws_size,
                              hipStream_t stream)
{
    (void)in_sizes; (void)n_in; (void)out_size; (void)ws_size;
    const float* x     = (const float*)d_in[0];
    const float* w1    = (const float*)d_in[1];
    const float* b1    = (const float*)d_in[2];
    const float* w2    = (const float*)d_in[3];
    const float* b2    = (const float*)d_in[4];
    const float* w3    = (const float*)d_in[5];
    const float* b3    = (const float*)d_in[6];
    const float* wp    = (const float*)d_in[7];
    const float* bp    = (const float*)d_in[8];
    const float* wfc   = (const float*)d_in[9];
    const float* wdep  = (const float*)d_in[10];
    const float* bdep  = (const float*)d_in[11];
    const float* rate1 = (const float*)d_in[12];
    const float* rate2 = (const float*)d_in[13];
    float* out = (float*)d_out;

    float* wsf = (float*)d_ws;
    float* q = wsf;                 // 2*64*8192 = 1,048,576 floats
    float* k = wsf + 1048576;
    float* v = wsf + 2097152;       // total 12 MB of ws

    qkv_kernel <<<512, 256, 0, stream>>>(x, w1, b1, w2, b2, w3, b3, q, k, v);
    att_kernel <<<256, 256, 0, stream>>>(q, k, v, wp, bp, rate1, out);
    conv_kernel<<<256, 256, 0, stream>>>(q, k, v, wfc, wdep, bdep, rate2, out);
}

// Round 2
// 145.061 us; speedup vs baseline: 1.1357x; 1.1357x over previous
//
#include <hip/hip_runtime.h>

// ACmix: b=2, C=64 (HEAD=4 x HEAD_DIM=16), (d,w,h)=(8,32,32), L=8192
// Attention view: (H2,W2)=(64,128). Conv view: (8, 1024). K_ATT=7 PAD=3.

// ---------------------------------------------------------------------------
// Kernel 1: fused q/k/v 1x1 convs + fc (f_all) computation.
// Block 512 thr = 8 waves; wave w owns hd pair {2w,2w+1} (readfirstlane ->
// weights take the s_load path). x tile [64ci][64l] staged in 16 KB LDS,
// broadcast b32 reads (2-way alias = free), 24 FMA per read.
// f[b,m,hd,l] = sum_hh wfc[m,hh]*q[hh*16+hd] + wfc[m,4+hh]*k + wfc[m,8+hh]*v
// is linear in the accumulators -> computed post-loop (216 FMA/thread).
// Grid: 2b * 128 ltiles = 256 blocks.
// ---------------------------------------------------------------------------
__global__ __launch_bounds__(512) void qkvf_kernel(
    const float* __restrict__ x,
    const float* __restrict__ w1, const float* __restrict__ b1,
    const float* __restrict__ w2, const float* __restrict__ b2,
    const float* __restrict__ w3, const float* __restrict__ b3,
    const float* __restrict__ wfc,
    float* __restrict__ q, float* __restrict__ k, float* __restrict__ v,
    float* __restrict__ f)
{
    __shared__ float xs[64][64];   // [ci][l]

    int bx    = blockIdx.x;
    int ltile = bx & 127;
    int b     = bx >> 7;
    int l0    = ltile * 64;

    // ---- stage x tile: 1024 float4, rows of 16 f4 (256 B) coalesced ----
    const float4* xg = (const float4*)(x + (size_t)b * 64 * 8192);
    for (int t = threadIdx.x; t < 1024; t += 512) {
        int ci = t >> 4, col = t & 15;
        float4 val = xg[ci * 2048 + (l0 >> 2) + col];
        *((float4*)&xs[ci][col * 4]) = val;
    }
    __syncthreads();

    int lane = threadIdx.x & 63;
    int wv   = __builtin_amdgcn_readfirstlane(threadIdx.x >> 6); // wave id, SGPR
    int l    = l0 + lane;

    float qa[4][2], ka[4][2], va[4][2];
#pragma unroll
    for (int hh = 0; hh < 4; ++hh)
#pragma unroll
        for (int p = 0; p < 2; ++p) {
            int c = hh * 16 + 2 * wv + p;
            qa[hh][p] = b1[c]; ka[hh][p] = b2[c]; va[hh][p] = b3[c];
        }

#pragma unroll 8
    for (int ci = 0; ci < 64; ++ci) {
        float xv = xs[ci][lane];
#pragma unroll
        for (int hh = 0; hh < 4; ++hh)
#pragma unroll
            for (int p = 0; p < 2; ++p) {
                int c = hh * 16 + 2 * wv + p;
                qa[hh][p] = fmaf(w1[c * 64 + ci], xv, qa[hh][p]);
                ka[hh][p] = fmaf(w2[c * 64 + ci], xv, ka[hh][p]);
                va[hh][p] = fmaf(w3[c * 64 + ci], xv, va[hh][p]);
            }
    }

    // ---- stores: q/k/v (24) ----
#pragma unroll
    for (int hh = 0; hh < 4; ++hh)
#pragma unroll
        for (int p = 0; p < 2; ++p) {
            int c = hh * 16 + 2 * wv + p;
            size_t o = (size_t)(b * 64 + c) * 8192 + l;
            q[o] = qa[hh][p]; k[o] = ka[hh][p]; v[o] = va[hh][p];
        }

    // ---- f_all: 9 m x 2 hd (18 values, 216 FMA) ----
#pragma unroll
    for (int m = 0; m < 9; ++m)
#pragma unroll
        for (int p = 0; p < 2; ++p) {
            float acc = 0.f;
#pragma unroll
            for (int hh = 0; hh < 4; ++hh) {
                acc = fmaf(wfc[m * 12 + 0 + hh], qa[hh][p], acc);
                acc = fmaf(wfc[m * 12 + 4 + hh], ka[hh][p], acc);
                acc = fmaf(wfc[m * 12 + 8 + hh], va[hh][p], acc);
            }
            int hd = 2 * wv + p;
            f[((size_t)(b * 9 + m) * 16 + hd) * 8192 + l] = acc;
        }
}

// ---------------------------------------------------------------------------
// Kernel 2: attention branch.  out = rate1 * out_att.
// LDS layout [y][x][16c] so fragment reads are 4x ds_read_b128 (16B aligned,
// lane stride 64 B -> 2-way alias, free).  kp = k - pe (q.pe_center cancels
// in softmax).  16x16 pixel tile per block, reflect halo +-3.
// ---------------------------------------------------------------------------
__global__ __launch_bounds__(256) void att_kernel(
    const float* __restrict__ q, const float* __restrict__ k,
    const float* __restrict__ v,
    const float* __restrict__ wp, const float* __restrict__ bp,
    const float* __restrict__ rate1p, float* __restrict__ out)
{
    __shared__ float kp[22][22][16];
    __shared__ float vt[22][22][16];

    int bx = blockIdx.x;          // 8 n * 4 yt * 8 xt = 256
    int xt = bx & 7;
    int yt = (bx >> 3) & 3;
    int n  = bx >> 5;
    int head = n & 3;
    int b    = n >> 2;
    int y0 = yt * 16, x0 = xt * 16;

    // ---- load tiles (coalesced runs of 22 along x; LDS writes transposed) --
    const int NELEM = 16 * 22 * 22;   // c slow, ty, tx fast
    for (int e = threadIdx.x; e < NELEM; e += 256) {
        int tx  = e % 22;
        int rem = e / 22;
        int ty  = rem % 22;
        int c   = rem / 22;
        int sy = y0 + ty - 3; if (sy < 0) sy = -sy; else if (sy >= 64)  sy = 126 - sy;
        int sx = x0 + tx - 3; if (sx < 0) sx = -sx; else if (sx >= 128) sx = 254 - sx;
        int l = sy * 128 + sx;
        size_t o = (size_t)(b * 64 + head * 16 + c) * 8192 + l;
        int dd = l >> 10, r2 = l & 1023, ww = r2 >> 5, hh = r2 & 31;
        float ld = dd * (2.0f / 7.0f)  - 1.0f;
        float lw = ww * (2.0f / 31.0f) - 1.0f;
        float lh = hh * (2.0f / 31.0f) - 1.0f;
        float pe = bp[c];
        pe = fmaf(wp[c * 3 + 0], ld, pe);
        pe = fmaf(wp[c * 3 + 1], lw, pe);
        pe = fmaf(wp[c * 3 + 2], lh, pe);
        kp[ty][tx][c] = k[o] - pe;
        vt[ty][tx][c] = v[o];
    }
    __syncthreads();

    int tx = threadIdx.x & 15, ty = threadIdx.x >> 4;
    int l = (y0 + ty) * 128 + (x0 + tx);

    float qc[16];
#pragma unroll
    for (int c = 0; c < 16; ++c)
        qc[c] = q[(size_t)(b * 64 + head * 16 + c) * 8192 + l] * 0.25f;

    float lg[49];
#pragma unroll
    for (int i = 0; i < 7; ++i)
#pragma unroll
        for (int j = 0; j < 7; ++j) {
            const float4* p = (const float4*)kp[ty + i][tx + j];
            float4 a = p[0], b4 = p[1], c4 = p[2], d4 = p[3];
            float acc =      qc[0]  * a.x;
            acc = fmaf(qc[1],  a.y,  acc); acc = fmaf(qc[2],  a.z,  acc);
            acc = fmaf(qc[3],  a.w,  acc); acc = fmaf(qc[4],  b4.x, acc);
            acc = fmaf(qc[5],  b4.y, acc); acc = fmaf(qc[6],  b4.z, acc);
            acc = fmaf(qc[7],  b4.w, acc); acc = fmaf(qc[8],  c4.x, acc);
            acc = fmaf(qc[9],  c4.y, acc); acc = fmaf(qc[10], c4.z, acc);
            acc = fmaf(qc[11], c4.w, acc); acc = fmaf(qc[12], d4.x, acc);
            acc = fmaf(qc[13], d4.y, acc); acc = fmaf(qc[14], d4.z, acc);
            acc = fmaf(qc[15], d4.w, acc);
            lg[i * 7 + j] = acc;
        }

    float mx = lg[0];
#pragma unroll
    for (int kk = 1; kk < 49; ++kk) mx = fmaxf(mx, lg[kk]);
    float se = 0.f;
#pragma unroll
    for (int kk = 0; kk < 49; ++kk) { lg[kk] = __expf(lg[kk] - mx); se += lg[kk]; }
    float scale = rate1p[0] / se;

    float oc[16];
#pragma unroll
    for (int c = 0; c < 16; ++c) oc[c] = 0.f;
#pragma unroll
    for (int i = 0; i < 7; ++i)
#pragma unroll
        for (int j = 0; j < 7; ++j) {
            float wgt = lg[i * 7 + j];
            const float4* p = (const float4*)vt[ty + i][tx + j];
            float4 a = p[0], b4 = p[1], c4 = p[2], d4 = p[3];
            oc[0]  = fmaf(wgt, a.x,  oc[0]);  oc[1]  = fmaf(wgt, a.y,  oc[1]);
            oc[2]  = fmaf(wgt, a.z,  oc[2]);  oc[3]  = fmaf(wgt, a.w,  oc[3]);
            oc[4]  = fmaf(wgt, b4.x, oc[4]);  oc[5]  = fmaf(wgt, b4.y, oc[5]);
            oc[6]  = fmaf(wgt, b4.z, oc[6]);  oc[7]  = fmaf(wgt, b4.w, oc[7]);
            oc[8]  = fmaf(wgt, c4.x, oc[8]);  oc[9]  = fmaf(wgt, c4.y, oc[9]);
            oc[10] = fmaf(wgt, c4.z, oc[10]); oc[11] = fmaf(wgt, c4.w, oc[11]);
            oc[12] = fmaf(wgt, d4.x, oc[12]); oc[13] = fmaf(wgt, d4.y, oc[13]);
            oc[14] = fmaf(wgt, d4.w == d4.w ? d4.z : d4.z, oc[14]); // d4.z
            oc[15] = fmaf(wgt, d4.w, oc[15]);
        }

#pragma unroll
    for (int c = 0; c < 16; ++c)
        out[(size_t)(b * 64 + head * 16 + c) * 8192 + l] = oc[c] * scale;
}

// ---------------------------------------------------------------------------
// Kernel 3: conv branch + combine.  out += rate2 * (depconv(f) + bdep).
// f precomputed by kernel 1 -> 1 coalesced load per LDS element.
// Block: (b, group g, x-tile 128).  ft[9][8][130] = 37.4 KB.
// Output channels 4g..4g+3 use f channels 9g..9g+8 (groups=16).
// ---------------------------------------------------------------------------
__global__ __launch_bounds__(256) void conv_kernel(
    const float* __restrict__ f,
    const float* __restrict__ wdep, const float* __restrict__ bdep,
    const float* __restrict__ rate2p, float* __restrict__ out)
{
    __shared__ float ft[9][8][130];

    int bx = blockIdx.x;          // 2 b * 16 g * 8 xt = 256
    int xt = bx & 7;
    int g  = (bx >> 3) & 15;
    int b  = bx >> 7;
    int x0 = xt * 128;

    const int NE = 9 * 8 * 130;
    for (int e = threadIdx.x; e < NE; e += 256) {
        int xx  = e % 130;
        int rem = e / 130;
        int y = rem % 8, i = rem / 8;
        int gx = x0 + xx - 1;     // zero pad at x2 edges
        float val = 0.f;
        if (gx >= 0 && gx < 1024) {
            int c144 = g * 9 + i;
            val = f[((size_t)(b * 144 + c144)) * 8192 + y * 1024 + gx];
        }
        ft[i][y][xx] = val;
    }
    __syncthreads();

    int xl = threadIdx.x & 127;
    int op = __builtin_amdgcn_readfirstlane(threadIdx.x >> 7); // wave-uniform
    float rate2 = rate2p[0];

    float acc[2][8];
#pragma unroll
    for (int oo = 0; oo < 2; ++oo)
#pragma unroll
        for (int y = 0; y < 8; ++y) acc[oo][y] = 0.f;

    for (int i = 0; i < 9; ++i) {
        float fr[10][3];
#pragma unroll
        for (int dx = 0; dx < 3; ++dx) { fr[0][dx] = 0.f; fr[9][dx] = 0.f; }
#pragma unroll
        for (int y = 0; y < 8; ++y)
#pragma unroll
            for (int dx = 0; dx < 3; ++dx)
                fr[y + 1][dx] = ft[i][y][xl + dx];
#pragma unroll
        for (int oo = 0; oo < 2; ++oo) {
            int o = g * 4 + op * 2 + oo;
#pragma unroll
            for (int ky = 0; ky < 3; ++ky)
#pragma unroll
                for (int kx = 0; kx < 3; ++kx) {
                    float wvv = wdep[((o * 9 + i) * 3 + ky) * 3 + kx];
#pragma unroll
                    for (int y = 0; y < 8; ++y)
                        acc[oo][y] = fmaf(wvv, fr[y + ky][kx], acc[oo][y]);
                }
        }
    }

#pragma unroll
    for (int oo = 0; oo < 2; ++oo) {
        int o = g * 4 + op * 2 + oo;
        float bd = bdep[o];
#pragma unroll
        for (int y = 0; y < 8; ++y) {
            size_t idx = (size_t)(b * 64 + o) * 8192 + y * 1024 + x0 + xl;
            out[idx] = out[idx] + rate2 * (acc[oo][y] + bd);
        }
    }
}

// ---------------------------------------------------------------------------
extern "C" void kernel_launch(void* const* d_in, const int* in_sizes, int n_in,
                              void* d_out, int out_size, void* d_ws, size_t ws_size,
                              hipStream_t stream)
{
    (void)in_sizes; (void)n_in; (void)out_size; (void)ws_size;
    const float* x     = (const float*)d_in[0];
    const float* w1    = (const float*)d_in[1];
    const float* b1    = (const float*)d_in[2];
    const float* w2    = (const float*)d_in[3];
    const float* b2    = (const float*)d_in[4];
    const float* w3    = (const float*)d_in[5];
    const float* b3    = (const float*)d_in[6];
    const float* wp    = (const float*)d_in[7];
    const float* bp    = (const float*)d_in[8];
    const float* wfc   = (const float*)d_in[9];
    const float* wdep  = (const float*)d_in[10];
    const float* bdep  = (const float*)d_in[11];
    const float* rate1 = (const float*)d_in[12];
    const float* rate2 = (const float*)d_in[13];
    float* out = (float*)d_out;

    float* wsf = (float*)d_ws;
    float* q = wsf;                 // 3 x 1,048,576 floats (q,k,v)
    float* k = wsf + 1048576;
    float* v = wsf + 2097152;
    float* f = wsf + 3145728;       // 2,359,296 floats; total ws ~22 MB

    qkvf_kernel<<<256, 512, 0, stream>>>(x, w1, b1, w2, b2, w3, b3, wfc,
                                         q, k, v, f);
    att_kernel <<<256, 256, 0, stream>>>(q, k, v, wp, bp, rate1, out);
    conv_kernel<<<256, 256, 0, stream>>>(f, wdep, bdep, rate2, out);
}

// Round 3
// 141.858 us; speedup vs baseline: 1.1614x; 1.0226x over previous
//
#include <hip/hip_runtime.h>

// ACmix: b=2, C=64 (HEAD=4 x HEAD_DIM=16), (d,w,h)=(8,32,32), L=8192
// Attention view: (H2,W2)=(64,128). Conv view: (8, 1024). K_ATT=7 PAD=3.

// ---------------------------------------------------------------------------
// Kernel 1: fused q/k/v 1x1 convs + fc (f_all).
// v3: weights staged in LDS (48 KB) and read as wave-uniform ds_read_b128
// broadcasts (4 FMA per b128) -- removes the R2 in-loop s_load storm
// (1536 scalar floats/wave couldn't fit SGPRs, forcing lgkmcnt drains).
// x tile [64ci][64l] in 16 KB LDS, b32 broadcast-ish reads (2-way = free).
// Wave w owns hd pair {2w, 2w+1}: 24 acc streams; f computed post-loop
// from the q/k/v accumulators (linear), 216 FMA/thread.
// Grid: 2b * 128 ltiles = 256 blocks x 512 thr.  LDS 64 KB.
// ---------------------------------------------------------------------------
__global__ __launch_bounds__(512) void qkvf_kernel(
    const float* __restrict__ x,
    const float* __restrict__ w1, const float* __restrict__ b1,
    const float* __restrict__ w2, const float* __restrict__ b2,
    const float* __restrict__ w3, const float* __restrict__ b3,
    const float* __restrict__ wfc,
    float* __restrict__ q, float* __restrict__ k, float* __restrict__ v,
    float* __restrict__ f)
{
    __shared__ float xs[64][64];        // [ci][l]       16 KB
    __shared__ float wlds[3][64][64];   // [mat][c][ci]  48 KB

    int bx    = blockIdx.x;
    int ltile = bx & 127;
    int b     = bx >> 7;
    int l0    = ltile * 64;

    // ---- stage weights: 3072 float4, coalesced ----
    {
        float4* wl = (float4*)wlds;
        for (int t = threadIdx.x; t < 3072; t += 512) {
            int m   = t >> 10;
            int idx = t & 1023;
            const float* src = (m == 0) ? w1 : (m == 1) ? w2 : w3;
            wl[t] = ((const float4*)src)[idx];
        }
    }
    // ---- stage x tile: 1024 float4, coalesced ----
    const float4* xg = (const float4*)(x + (size_t)b * 64 * 8192);
    for (int t = threadIdx.x; t < 1024; t += 512) {
        int ci = t >> 4, col = t & 15;
        *((float4*)&xs[ci][col * 4]) = xg[ci * 2048 + (l0 >> 2) + col];
    }
    __syncthreads();

    int lane = threadIdx.x & 63;
    int wv   = __builtin_amdgcn_readfirstlane(threadIdx.x >> 6); // wave id
    int l    = l0 + lane;
    int hd0  = 2 * wv;

    float qa[4][2], ka[4][2], va[4][2];
#pragma unroll
    for (int hh = 0; hh < 4; ++hh)
#pragma unroll
        for (int p = 0; p < 2; ++p) {
            int c = hh * 16 + hd0 + p;
            qa[hh][p] = b1[c]; ka[hh][p] = b2[c]; va[hh][p] = b3[c];
        }

#pragma unroll 4
    for (int c4 = 0; c4 < 16; ++c4) {
        float xv[4];
#pragma unroll
        for (int u = 0; u < 4; ++u) xv[u] = xs[c4 * 4 + u][lane];
#pragma unroll
        for (int hh = 0; hh < 4; ++hh)
#pragma unroll
            for (int p = 0; p < 2; ++p) {
                int c = hh * 16 + hd0 + p;
                float4 wq = *(const float4*)&wlds[0][c][c4 * 4];
                float4 wk = *(const float4*)&wlds[1][c][c4 * 4];
                float4 wx = *(const float4*)&wlds[2][c][c4 * 4];
                qa[hh][p] = fmaf(wq.x, xv[0], qa[hh][p]);
                qa[hh][p] = fmaf(wq.y, xv[1], qa[hh][p]);
                qa[hh][p] = fmaf(wq.z, xv[2], qa[hh][p]);
                qa[hh][p] = fmaf(wq.w, xv[3], qa[hh][p]);
                ka[hh][p] = fmaf(wk.x, xv[0], ka[hh][p]);
                ka[hh][p] = fmaf(wk.y, xv[1], ka[hh][p]);
                ka[hh][p] = fmaf(wk.z, xv[2], ka[hh][p]);
                ka[hh][p] = fmaf(wk.w, xv[3], ka[hh][p]);
                va[hh][p] = fmaf(wx.x, xv[0], va[hh][p]);
                va[hh][p] = fmaf(wx.y, xv[1], va[hh][p]);
                va[hh][p] = fmaf(wx.z, xv[2], va[hh][p]);
                va[hh][p] = fmaf(wx.w, xv[3], va[hh][p]);
            }
    }

    // ---- stores: q/k/v (24, coalesced over lane=l) ----
#pragma unroll
    for (int hh = 0; hh < 4; ++hh)
#pragma unroll
        for (int p = 0; p < 2; ++p) {
            int c = hh * 16 + hd0 + p;
            size_t o = (size_t)(b * 64 + c) * 8192 + l;
            q[o] = qa[hh][p]; k[o] = ka[hh][p]; v[o] = va[hh][p];
        }

    // ---- f_all: 9 m x 2 hd (18 values, 216 FMA) ----
#pragma unroll
    for (int m = 0; m < 9; ++m)
#pragma unroll
        for (int p = 0; p < 2; ++p) {
            float acc = 0.f;
#pragma unroll
            for (int hh = 0; hh < 4; ++hh) {
                acc = fmaf(wfc[m * 12 + 0 + hh], qa[hh][p], acc);
                acc = fmaf(wfc[m * 12 + 4 + hh], ka[hh][p], acc);
                acc = fmaf(wfc[m * 12 + 8 + hh], va[hh][p], acc);
            }
            int hd = hd0 + p;
            f[((size_t)(b * 9 + m) * 16 + hd) * 8192 + l] = acc;
        }
}

// ---------------------------------------------------------------------------
// Kernel 2: attention branch.  out = rate1 * out_att.
// LDS layout [y][x][16c]: fragment reads are 4x ds_read_b128 (16B aligned,
// lane stride 64 B -> 2-way alias, free).  kp = k - pe (q.pe_center cancels
// in softmax).  16x16 pixel tile per block, reflect halo +-3.
// ---------------------------------------------------------------------------
__global__ __launch_bounds__(256) void att_kernel(
    const float* __restrict__ q, const float* __restrict__ k,
    const float* __restrict__ v,
    const float* __restrict__ wp, const float* __restrict__ bp,
    const float* __restrict__ rate1p, float* __restrict__ out)
{
    __shared__ float kp[22][22][16];
    __shared__ float vt[22][22][16];

    int bx = blockIdx.x;          // 8 n * 4 yt * 8 xt = 256
    int xt = bx & 7;
    int yt = (bx >> 3) & 3;
    int n  = bx >> 5;
    int head = n & 3;
    int b    = n >> 2;
    int y0 = yt * 16, x0 = xt * 16;

    const int NELEM = 16 * 22 * 22;   // c slow, ty, tx fast
    for (int e = threadIdx.x; e < NELEM; e += 256) {
        int tx  = e % 22;
        int rem = e / 22;
        int ty  = rem % 22;
        int c   = rem / 22;
        int sy = y0 + ty - 3; if (sy < 0) sy = -sy; else if (sy >= 64)  sy = 126 - sy;
        int sx = x0 + tx - 3; if (sx < 0) sx = -sx; else if (sx >= 128) sx = 254 - sx;
        int l = sy * 128 + sx;
        size_t o = (size_t)(b * 64 + head * 16 + c) * 8192 + l;
        int dd = l >> 10, r2 = l & 1023, ww = r2 >> 5, hh = r2 & 31;
        float ld = dd * (2.0f / 7.0f)  - 1.0f;
        float lw = ww * (2.0f / 31.0f) - 1.0f;
        float lh = hh * (2.0f / 31.0f) - 1.0f;
        float pe = bp[c];
        pe = fmaf(wp[c * 3 + 0], ld, pe);
        pe = fmaf(wp[c * 3 + 1], lw, pe);
        pe = fmaf(wp[c * 3 + 2], lh, pe);
        kp[ty][tx][c] = k[o] - pe;
        vt[ty][tx][c] = v[o];
    }
    __syncthreads();

    int tx = threadIdx.x & 15, ty = threadIdx.x >> 4;
    int l = (y0 + ty) * 128 + (x0 + tx);

    float qc[16];
#pragma unroll
    for (int c = 0; c < 16; ++c)
        qc[c] = q[(size_t)(b * 64 + head * 16 + c) * 8192 + l] * 0.25f;

    float lg[49];
#pragma unroll
    for (int i = 0; i < 7; ++i)
#pragma unroll
        for (int j = 0; j < 7; ++j) {
            const float4* p = (const float4*)kp[ty + i][tx + j];
            float4 a = p[0], b4 = p[1], c4 = p[2], d4 = p[3];
            float acc =      qc[0]  * a.x;
            acc = fmaf(qc[1],  a.y,  acc); acc = fmaf(qc[2],  a.z,  acc);
            acc = fmaf(qc[3],  a.w,  acc); acc = fmaf(qc[4],  b4.x, acc);
            acc = fmaf(qc[5],  b4.y, acc); acc = fmaf(qc[6],  b4.z, acc);
            acc = fmaf(qc[7],  b4.w, acc); acc = fmaf(qc[8],  c4.x, acc);
            acc = fmaf(qc[9],  c4.y, acc); acc = fmaf(qc[10], c4.z, acc);
            acc = fmaf(qc[11], c4.w, acc); acc = fmaf(qc[12], d4.x, acc);
            acc = fmaf(qc[13], d4.y, acc); acc = fmaf(qc[14], d4.z, acc);
            acc = fmaf(qc[15], d4.w, acc);
            lg[i * 7 + j] = acc;
        }

    float mx = lg[0];
#pragma unroll
    for (int kk = 1; kk < 49; ++kk) mx = fmaxf(mx, lg[kk]);
    float se = 0.f;
#pragma unroll
    for (int kk = 0; kk < 49; ++kk) { lg[kk] = __expf(lg[kk] - mx); se += lg[kk]; }
    float scale = rate1p[0] / se;

    float oc[16];
#pragma unroll
    for (int c = 0; c < 16; ++c) oc[c] = 0.f;
#pragma unroll
    for (int i = 0; i < 7; ++i)
#pragma unroll
        for (int j = 0; j < 7; ++j) {
            float wgt = lg[i * 7 + j];
            const float4* p = (const float4*)vt[ty + i][tx + j];
            float4 a = p[0], b4 = p[1], c4 = p[2], d4 = p[3];
            oc[0]  = fmaf(wgt, a.x,  oc[0]);  oc[1]  = fmaf(wgt, a.y,  oc[1]);
            oc[2]  = fmaf(wgt, a.z,  oc[2]);  oc[3]  = fmaf(wgt, a.w,  oc[3]);
            oc[4]  = fmaf(wgt, b4.x, oc[4]);  oc[5]  = fmaf(wgt, b4.y, oc[5]);
            oc[6]  = fmaf(wgt, b4.z, oc[6]);  oc[7]  = fmaf(wgt, b4.w, oc[7]);
            oc[8]  = fmaf(wgt, c4.x, oc[8]);  oc[9]  = fmaf(wgt, c4.y, oc[9]);
            oc[10] = fmaf(wgt, c4.z, oc[10]); oc[11] = fmaf(wgt, c4.w, oc[11]);
            oc[12] = fmaf(wgt, d4.x, oc[12]); oc[13] = fmaf(wgt, d4.y, oc[13]);
            oc[14] = fmaf(wgt, d4.z, oc[14]); oc[15] = fmaf(wgt, d4.w, oc[15]);
        }

#pragma unroll
    for (int c = 0; c < 16; ++c)
        out[(size_t)(b * 64 + head * 16 + c) * 8192 + l] = oc[c] * scale;
}

// ---------------------------------------------------------------------------
// Kernel 3: conv branch + combine.  out += rate2 * (depconv(f) + bdep).
// f precomputed by kernel 1 -> 1 coalesced load per LDS element.
// Block: (b, group g, x-tile 128).  ft[9][8][130] = 37.4 KB.
// ---------------------------------------------------------------------------
__global__ __launch_bounds__(256) void conv_kernel(
    const float* __restrict__ f,
    const float* __restrict__ wdep, const float* __restrict__ bdep,
    const float* __restrict__ rate2p, float* __restrict__ out)
{
    __shared__ float ft[9][8][130];

    int bx = blockIdx.x;          // 2 b * 16 g * 8 xt = 256
    int xt = bx & 7;
    int g  = (bx >> 3) & 15;
    int b  = bx >> 7;
    int x0 = xt * 128;

    const int NE = 9 * 8 * 130;
    for (int e = threadIdx.x; e < NE; e += 256) {
        int xx  = e % 130;
        int rem = e / 130;
        int y = rem % 8, i = rem / 8;
        int gx = x0 + xx - 1;     // zero pad at x2 edges
        float val = 0.f;
        if (gx >= 0 && gx < 1024) {
            int c144 = g * 9 + i;
            val = f[((size_t)(b * 144 + c144)) * 8192 + y * 1024 + gx];
        }
        ft[i][y][xx] = val;
    }
    __syncthreads();

    int xl = threadIdx.x & 127;
    int op = __builtin_amdgcn_readfirstlane(threadIdx.x >> 7);
    float rate2 = rate2p[0];

    float acc[2][8];
#pragma unroll
    for (int oo = 0; oo < 2; ++oo)
#pragma unroll
        for (int y = 0; y < 8; ++y) acc[oo][y] = 0.f;

    for (int i = 0; i < 9; ++i) {
        float fr[10][3];
#pragma unroll
        for (int dx = 0; dx < 3; ++dx) { fr[0][dx] = 0.f; fr[9][dx] = 0.f; }
#pragma unroll
        for (int y = 0; y < 8; ++y)
#pragma unroll
            for (int dx = 0; dx < 3; ++dx)
                fr[y + 1][dx] = ft[i][y][xl + dx];
#pragma unroll
        for (int oo = 0; oo < 2; ++oo) {
            int o = g * 4 + op * 2 + oo;
#pragma unroll
            for (int ky = 0; ky < 3; ++ky)
#pragma unroll
                for (int kx = 0; kx < 3; ++kx) {
                    float wvv = wdep[((o * 9 + i) * 3 + ky) * 3 + kx];
#pragma unroll
                    for (int y = 0; y < 8; ++y)
                        acc[oo][y] = fmaf(wvv, fr[y + ky][kx], acc[oo][y]);
                }
        }
    }

#pragma unroll
    for (int oo = 0; oo < 2; ++oo) {
        int o = g * 4 + op * 2 + oo;
        float bd = bdep[o];
#pragma unroll
        for (int y = 0; y < 8; ++y) {
            size_t idx = (size_t)(b * 64 + o) * 8192 + y * 1024 + x0 + xl;
            out[idx] = out[idx] + rate2 * (acc[oo][y] + bd);
        }
    }
}

// ---------------------------------------------------------------------------
extern "C" void kernel_launch(void* const* d_in, const int* in_sizes, int n_in,
                              void* d_out, int out_size, void* d_ws, size_t ws_size,
                              hipStream_t stream)
{
    (void)in_sizes; (void)n_in; (void)out_size; (void)ws_size;
    const float* x     = (const float*)d_in[0];
    const float* w1    = (const float*)d_in[1];
    const float* b1    = (const float*)d_in[2];
    const float* w2    = (const float*)d_in[3];
    const float* b2    = (const float*)d_in[4];
    const float* w3    = (const float*)d_in[5];
    const float* b3    = (const float*)d_in[6];
    const float* wp    = (const float*)d_in[7];
    const float* bp    = (const float*)d_in[8];
    const float* wfc   = (const float*)d_in[9];
    const float* wdep  = (const float*)d_in[10];
    const float* bdep  = (const float*)d_in[11];
    const float* rate1 = (const float*)d_in[12];
    const float* rate2 = (const float*)d_in[13];
    float* out = (float*)d_out;

    float* wsf = (float*)d_ws;
    float* q = wsf;                 // 3 x 1,048,576 floats (q,k,v)
    float* k = wsf + 1048576;
    float* v = wsf + 2097152;
    float* f = wsf + 3145728;       // 2,359,296 floats

    qkvf_kernel<<<256, 512, 0, stream>>>(x, w1, b1, w2, b2, w3, b3, wfc,
                                         q, k, v, f);
    att_kernel <<<256, 256, 0, stream>>>(q, k, v, wp, bp, rate1, out);
    conv_kernel<<<256, 256, 0, stream>>>(f, wdep, bdep, rate2, out);
}

// Round 4
// 139.519 us; speedup vs baseline: 1.1808x; 1.0168x over previous
//
#include <hip/hip_runtime.h>

// ACmix: b=2, C=64 (HEAD=4 x HEAD_DIM=16), (d,w,h)=(8,32,32), L=8192
// Attention view: (H2,W2)=(64,128). Conv view: (8, 1024). K_ATT=7 PAD=3.

// ---------------------------------------------------------------------------
// Kernel 1: fused q/k/v 1x1 convs + fc (f_all).
// Weights staged in LDS (48 KB), read as wave-uniform ds_read_b128 broadcasts
// (conflict-free same-address). x tile [64ci][64l] in 16 KB LDS.
// Wave w owns hd pair {2w, 2w+1}; f computed post-loop from accumulators.
// Grid: 2b * 128 ltiles = 256 blocks x 512 thr.  LDS 64 KB.
// ---------------------------------------------------------------------------
__global__ __launch_bounds__(512) void qkvf_kernel(
    const float* __restrict__ x,
    const float* __restrict__ w1, const float* __restrict__ b1,
    const float* __restrict__ w2, const float* __restrict__ b2,
    const float* __restrict__ w3, const float* __restrict__ b3,
    const float* __restrict__ wfc,
    float* __restrict__ q, float* __restrict__ k, float* __restrict__ v,
    float* __restrict__ f)
{
    __shared__ float xs[64][64];        // [ci][l]       16 KB
    __shared__ float wlds[3][64][64];   // [mat][c][ci]  48 KB

    int bx    = blockIdx.x;
    int ltile = bx & 127;
    int b     = bx >> 7;
    int l0    = ltile * 64;

    {
        float4* wl = (float4*)wlds;
        for (int t = threadIdx.x; t < 3072; t += 512) {
            int m   = t >> 10;
            int idx = t & 1023;
            const float* src = (m == 0) ? w1 : (m == 1) ? w2 : w3;
            wl[t] = ((const float4*)src)[idx];
        }
    }
    const float4* xg = (const float4*)(x + (size_t)b * 64 * 8192);
    for (int t = threadIdx.x; t < 1024; t += 512) {
        int ci = t >> 4, col = t & 15;
        *((float4*)&xs[ci][col * 4]) = xg[ci * 2048 + (l0 >> 2) + col];
    }
    __syncthreads();

    int lane = threadIdx.x & 63;
    int wv   = __builtin_amdgcn_readfirstlane(threadIdx.x >> 6);
    int l    = l0 + lane;
    int hd0  = 2 * wv;

    float qa[4][2], ka[4][2], va[4][2];
#pragma unroll
    for (int hh = 0; hh < 4; ++hh)
#pragma unroll
        for (int p = 0; p < 2; ++p) {
            int c = hh * 16 + hd0 + p;
            qa[hh][p] = b1[c]; ka[hh][p] = b2[c]; va[hh][p] = b3[c];
        }

#pragma unroll 4
    for (int c4 = 0; c4 < 16; ++c4) {
        float xv[4];
#pragma unroll
        for (int u = 0; u < 4; ++u) xv[u] = xs[c4 * 4 + u][lane];
#pragma unroll
        for (int hh = 0; hh < 4; ++hh)
#pragma unroll
            for (int p = 0; p < 2; ++p) {
                int c = hh * 16 + hd0 + p;
                float4 wq = *(const float4*)&wlds[0][c][c4 * 4];
                float4 wk = *(const float4*)&wlds[1][c][c4 * 4];
                float4 wx = *(const float4*)&wlds[2][c][c4 * 4];
                qa[hh][p] = fmaf(wq.x, xv[0], qa[hh][p]);
                qa[hh][p] = fmaf(wq.y, xv[1], qa[hh][p]);
                qa[hh][p] = fmaf(wq.z, xv[2], qa[hh][p]);
                qa[hh][p] = fmaf(wq.w, xv[3], qa[hh][p]);
                ka[hh][p] = fmaf(wk.x, xv[0], ka[hh][p]);
                ka[hh][p] = fmaf(wk.y, xv[1], ka[hh][p]);
                ka[hh][p] = fmaf(wk.z, xv[2], ka[hh][p]);
                ka[hh][p] = fmaf(wk.w, xv[3], ka[hh][p]);
                va[hh][p] = fmaf(wx.x, xv[0], va[hh][p]);
                va[hh][p] = fmaf(wx.y, xv[1], va[hh][p]);
                va[hh][p] = fmaf(wx.z, xv[2], va[hh][p]);
                va[hh][p] = fmaf(wx.w, xv[3], va[hh][p]);
            }
    }

#pragma unroll
    for (int hh = 0; hh < 4; ++hh)
#pragma unroll
        for (int p = 0; p < 2; ++p) {
            int c = hh * 16 + hd0 + p;
            size_t o = (size_t)(b * 64 + c) * 8192 + l;
            q[o] = qa[hh][p]; k[o] = ka[hh][p]; v[o] = va[hh][p];
        }

#pragma unroll
    for (int m = 0; m < 9; ++m)
#pragma unroll
        for (int p = 0; p < 2; ++p) {
            float acc = 0.f;
#pragma unroll
            for (int hh = 0; hh < 4; ++hh) {
                acc = fmaf(wfc[m * 12 + 0 + hh], qa[hh][p], acc);
                acc = fmaf(wfc[m * 12 + 4 + hh], ka[hh][p], acc);
                acc = fmaf(wfc[m * 12 + 8 + hh], va[hh][p], acc);
            }
            int hd = hd0 + p;
            f[((size_t)(b * 9 + m) * 16 + hd) * 8192 + l] = acc;
        }
}

// ---------------------------------------------------------------------------
// Kernel 2: attention branch.  out = rate1 * out_att.
// LDS layout [22][22][20]: channel dim PADDED 16 -> 20 floats (80 B stride,
// 16B-aligned).  Bank starts (20*X)%32 cycle {0,20,8,28,16,4,24,12} -- 8
// disjoint 4-bank groups covering all 32 banks; ty-row offset 440%32=24
// preserves alignment => every ds_read_b128 hits each bank exactly 8x =
// conflict-free minimum.  (R1/R2's [..][16] put ALL lanes on banks {0-3} or
// {16-19}: ~4x LDS-pipe penalty.)
// kp = k - pe (q.pe_center cancels in softmax).  16x16 tile, halo +-3.
// ---------------------------------------------------------------------------
__global__ __launch_bounds__(256) void att_kernel(
    const float* __restrict__ q, const float* __restrict__ k,
    const float* __restrict__ v,
    const float* __restrict__ wp, const float* __restrict__ bp,
    const float* __restrict__ rate1p, float* __restrict__ out)
{
    __shared__ float kp[22][22][20];   // 38.7 KB
    __shared__ float vt[22][22][20];   // 38.7 KB

    int bx = blockIdx.x;          // 8 n * 4 yt * 8 xt = 256
    int xt = bx & 7;
    int yt = (bx >> 3) & 3;
    int n  = bx >> 5;
    int head = n & 3;
    int b    = n >> 2;
    int y0 = yt * 16, x0 = xt * 16;

    const int NELEM = 16 * 22 * 22;   // c slow; ty, tx fast
    for (int e = threadIdx.x; e < NELEM; e += 256) {
        int tx  = e % 22;
        int rem = e / 22;
        int ty  = rem % 22;
        int c   = rem / 22;
        int sy = y0 + ty - 3; if (sy < 0) sy = -sy; else if (sy >= 64)  sy = 126 - sy;
        int sx = x0 + tx - 3; if (sx < 0) sx = -sx; else if (sx >= 128) sx = 254 - sx;
        int l = sy * 128 + sx;
        size_t o = (size_t)(b * 64 + head * 16 + c) * 8192 + l;
        int dd = l >> 10, r2 = l & 1023, ww = r2 >> 5, hh = r2 & 31;
        float ld = dd * (2.0f / 7.0f)  - 1.0f;
        float lw = ww * (2.0f / 31.0f) - 1.0f;
        float lh = hh * (2.0f / 31.0f) - 1.0f;
        float pe = bp[c];
        pe = fmaf(wp[c * 3 + 0], ld, pe);
        pe = fmaf(wp[c * 3 + 1], lw, pe);
        pe = fmaf(wp[c * 3 + 2], lh, pe);
        kp[ty][tx][c] = k[o] - pe;
        vt[ty][tx][c] = v[o];
    }
    __syncthreads();

    int tx = threadIdx.x & 15, ty = threadIdx.x >> 4;
    int l = (y0 + ty) * 128 + (x0 + tx);

    float qc[16];
#pragma unroll
    for (int c = 0; c < 16; ++c)
        qc[c] = q[(size_t)(b * 64 + head * 16 + c) * 8192 + l] * 0.25f;

    float lg[49];
#pragma unroll
    for (int i = 0; i < 7; ++i)
#pragma unroll
        for (int j = 0; j < 7; ++j) {
            const float4* p = (const float4*)&kp[ty + i][tx + j][0];
            float4 a = p[0], b4 = p[1], c4 = p[2], d4 = p[3];
            float acc =      qc[0]  * a.x;
            acc = fmaf(qc[1],  a.y,  acc); acc = fmaf(qc[2],  a.z,  acc);
            acc = fmaf(qc[3],  a.w,  acc); acc = fmaf(qc[4],  b4.x, acc);
            acc = fmaf(qc[5],  b4.y, acc); acc = fmaf(qc[6],  b4.z, acc);
            acc = fmaf(qc[7],  b4.w, acc); acc = fmaf(qc[8],  c4.x, acc);
            acc = fmaf(qc[9],  c4.y, acc); acc = fmaf(qc[10], c4.z, acc);
            acc = fmaf(qc[11], c4.w, acc); acc = fmaf(qc[12], d4.x, acc);
            acc = fmaf(qc[13], d4.y, acc); acc = fmaf(qc[14], d4.z, acc);
            acc = fmaf(qc[15], d4.w, acc);
            lg[i * 7 + j] = acc;
        }

    float mx = lg[0];
#pragma unroll
    for (int kk = 1; kk < 49; ++kk) mx = fmaxf(mx, lg[kk]);
    float se = 0.f;
#pragma unroll
    for (int kk = 0; kk < 49; ++kk) { lg[kk] = __expf(lg[kk] - mx); se += lg[kk]; }
    float scale = rate1p[0] / se;

    float oc[16];
#pragma unroll
    for (int c = 0; c < 16; ++c) oc[c] = 0.f;
#pragma unroll
    for (int i = 0; i < 7; ++i)
#pragma unroll
        for (int j = 0; j < 7; ++j) {
            float wgt = lg[i * 7 + j];
            const float4* p = (const float4*)&vt[ty + i][tx + j][0];
            float4 a = p[0], b4 = p[1], c4 = p[2], d4 = p[3];
            oc[0]  = fmaf(wgt, a.x,  oc[0]);  oc[1]  = fmaf(wgt, a.y,  oc[1]);
            oc[2]  = fmaf(wgt, a.z,  oc[2]);  oc[3]  = fmaf(wgt, a.w,  oc[3]);
            oc[4]  = fmaf(wgt, b4.x, oc[4]);  oc[5]  = fmaf(wgt, b4.y, oc[5]);
            oc[6]  = fmaf(wgt, b4.z, oc[6]);  oc[7]  = fmaf(wgt, b4.w, oc[7]);
            oc[8]  = fmaf(wgt, c4.x, oc[8]);  oc[9]  = fmaf(wgt, c4.y, oc[9]);
            oc[10] = fmaf(wgt, c4.z, oc[10]); oc[11] = fmaf(wgt, c4.w, oc[11]);
            oc[12] = fmaf(wgt, d4.x, oc[12]); oc[13] = fmaf(wgt, d4.y, oc[13]);
            oc[14] = fmaf(wgt, d4.z, oc[14]); oc[15] = fmaf(wgt, d4.w, oc[15]);
        }

#pragma unroll
    for (int c = 0; c < 16; ++c)
        out[(size_t)(b * 64 + head * 16 + c) * 8192 + l] = oc[c] * scale;
}

// ---------------------------------------------------------------------------
// Kernel 3: conv branch + combine.  out += rate2 * (depconv(f) + bdep).
// ft[9][8][130]; compute reads are lane-consecutive b32 -> conflict-free.
// ---------------------------------------------------------------------------
__global__ __launch_bounds__(256) void conv_kernel(
    const float* __restrict__ f,
    const float* __restrict__ wdep, const float* __restrict__ bdep,
    const float* __restrict__ rate2p, float* __restrict__ out)
{
    __shared__ float ft[9][8][130];

    int bx = blockIdx.x;          // 2 b * 16 g * 8 xt = 256
    int xt = bx & 7;
    int g  = (bx >> 3) & 15;
    int b  = bx >> 7;
    int x0 = xt * 128;

    const int NE = 9 * 8 * 130;
    for (int e = threadIdx.x; e < NE; e += 256) {
        int xx  = e % 130;
        int rem = e / 130;
        int y = rem % 8, i = rem / 8;
        int gx = x0 + xx - 1;
        float val = 0.f;
        if (gx >= 0 && gx < 1024) {
            int c144 = g * 9 + i;
            val = f[((size_t)(b * 144 + c144)) * 8192 + y * 1024 + gx];
        }
        ft[i][y][xx] = val;
    }
    __syncthreads();

    int xl = threadIdx.x & 127;
    int op = __builtin_amdgcn_readfirstlane(threadIdx.x >> 7);
    float rate2 = rate2p[0];

    float acc[2][8];
#pragma unroll
    for (int oo = 0; oo < 2; ++oo)
#pragma unroll
        for (int y = 0; y < 8; ++y) acc[oo][y] = 0.f;

    for (int i = 0; i < 9; ++i) {
        float fr[10][3];
#pragma unroll
        for (int dx = 0; dx < 3; ++dx) { fr[0][dx] = 0.f; fr[9][dx] = 0.f; }
#pragma unroll
        for (int y = 0; y < 8; ++y)
#pragma unroll
            for (int dx = 0; dx < 3; ++dx)
                fr[y + 1][dx] = ft[i][y][xl + dx];
#pragma unroll
        for (int oo = 0; oo < 2; ++oo) {
            int o = g * 4 + op * 2 + oo;
#pragma unroll
            for (int ky = 0; ky < 3; ++ky)
#pragma unroll
                for (int kx = 0; kx < 3; ++kx) {
                    float wvv = wdep[((o * 9 + i) * 3 + ky) * 3 + kx];
#pragma unroll
                    for (int y = 0; y < 8; ++y)
                        acc[oo][y] = fmaf(wvv, fr[y + ky][kx], acc[oo][y]);
                }
        }
    }

#pragma unroll
    for (int oo = 0; oo < 2; ++oo) {
        int o = g * 4 + op * 2 + oo;
        float bd = bdep[o];
#pragma unroll
        for (int y = 0; y < 8; ++y) {
            size_t idx = (size_t)(b * 64 + o) * 8192 + y * 1024 + x0 + xl;
            out[idx] = out[idx] + rate2 * (acc[oo][y] + bd);
        }
    }
}

// ---------------------------------------------------------------------------
extern "C" void kernel_launch(void* const* d_in, const int* in_sizes, int n_in,
                              void* d_out, int out_size, void* d_ws, size_t ws_size,
                              hipStream_t stream)
{
    (void)in_sizes; (void)n_in; (void)out_size; (void)ws_size;
    const float* x     = (const float*)d_in[0];
    const float* w1    = (const float*)d_in[1];
    const float* b1    = (const float*)d_in[2];
    const float* w2    = (const float*)d_in[3];
    const float* b2    = (const float*)d_in[4];
    const float* w3    = (const float*)d_in[5];
    const float* b3    = (const float*)d_in[6];
    const float* wp    = (const float*)d_in[7];
    const float* bp    = (const float*)d_in[8];
    const float* wfc   = (const float*)d_in[9];
    const float* wdep  = (const float*)d_in[10];
    const float* bdep  = (const float*)d_in[11];
    const float* rate1 = (const float*)d_in[12];
    const float* rate2 = (const float*)d_in[13];
    float* out = (float*)d_out;

    float* wsf = (float*)d_ws;
    float* q = wsf;                 // 3 x 1,048,576 floats (q,k,v)
    float* k = wsf + 1048576;
    float* v = wsf + 2097152;
    float* f = wsf + 3145728;       // 2,359,296 floats

    qkvf_kernel<<<256, 512, 0, stream>>>(x, w1, b1, w2, b2, w3, b3, wfc,
                                         q, k, v, f);
    att_kernel <<<256, 256, 0, stream>>>(q, k, v, wp, bp, rate1, out);
    conv_kernel<<<256, 256, 0, stream>>>(f, wdep, bdep, rate2, out);
}